// Round 1
// baseline (2373.866 us; speedup 1.0000x reference)
//
#include <hip/hip_runtime.h>
#include <math.h>

#define NN 50000
#define EE 500000
#define DD 128
#define KK 5
#define LL 2

// ===================== graph preprocessing =====================

__global__ __launch_bounds__(256) void edge_pass1(
    const int* __restrict__ src, const int* __restrict__ dst,
    const float* __restrict__ ew,
    float* __restrict__ deg, int* __restrict__ hist)
{
    int e = blockIdx.x * blockDim.x + threadIdx.x;
    if (e >= EE) return;
    atomicAdd(&deg[src[e]], ew[e]);
    atomicAdd(&hist[dst[e]], 1);
}

__global__ __launch_bounds__(256) void dinv_kernel(
    const float* __restrict__ deg, float* __restrict__ dinv)
{
    int i = blockIdx.x * blockDim.x + threadIdx.x;
    if (i >= NN) return;
    float d = deg[i];
    dinv[i] = (d > 0.f) ? (1.f / sqrtf(d)) : 0.f;
}

__global__ __launch_bounds__(1024) void scan_kernel(
    const int* __restrict__ hist, int* __restrict__ row_ptr)
{
    __shared__ int buf[1024];
    __shared__ int carry;
    int tid = threadIdx.x;
    if (tid == 0) { carry = 0; row_ptr[0] = 0; }
    __syncthreads();
    for (int base = 0; base < NN; base += 1024) {
        int i = base + tid;
        int v = (i < NN) ? hist[i] : 0;
        buf[tid] = v;
        __syncthreads();
        for (int off = 1; off < 1024; off <<= 1) {
            int t = (tid >= off) ? buf[tid - off] : 0;
            __syncthreads();
            buf[tid] += t;
            __syncthreads();
        }
        int incl = buf[tid] + carry;
        if (i < NN) row_ptr[i + 1] = incl;
        __syncthreads();
        if (tid == 1023) carry = incl;
        __syncthreads();
    }
}

__global__ __launch_bounds__(256) void copy_fill(
    const int* __restrict__ row_ptr, int* __restrict__ fill)
{
    int i = blockIdx.x * blockDim.x + threadIdx.x;
    if (i < NN) fill[i] = row_ptr[i];
}

__global__ __launch_bounds__(256) void edge_scatter(
    const int* __restrict__ src, const int* __restrict__ dst,
    const float* __restrict__ ew, const float* __restrict__ dinv,
    int* __restrict__ fill,
    int* __restrict__ src_srt, float* __restrict__ w_srt)
{
    int e = blockIdx.x * blockDim.x + threadIdx.x;
    if (e >= EE) return;
    int s = src[e], t = dst[e];
    float w = -dinv[s] * ew[e] * dinv[t];
    int pos = atomicAdd(&fill[t], 1);
    src_srt[pos] = s;
    w_srt[pos] = w;
}

// ===================== scalar Chebyshev vectors (for H = ones) =====================
// tout[i] = alpha * sum_{e in row i} w[e]*tin[src[e]]  + beta * prev[i]
__global__ __launch_bounds__(256) void propv_kernel(
    const int* __restrict__ rp, const int* __restrict__ ss, const float* __restrict__ sw,
    const float* __restrict__ tin, const float* __restrict__ tprev, float* __restrict__ tout,
    float alpha, float beta, int ones_in, int ones_prev)
{
    int i = blockIdx.x * blockDim.x + threadIdx.x;
    if (i >= NN) return;
    float acc = 0.f;
    int e0 = rp[i], e1 = rp[i + 1];
    for (int e = e0; e < e1; ++e) {
        float tv = ones_in ? 1.f : tin[ss[e]];
        acc += sw[e] * tv;
    }
    float pv = ones_prev ? 1.f : (tprev ? tprev[i] : 0.f);
    tout[i] = alpha * acc + beta * pv;
}

// colsum of Wh[l, g(0..1), k] -> scol[(l*2+g)*K + k][d]
__global__ __launch_bounds__(128) void colsum_kernel(
    const float* __restrict__ Wh, float* __restrict__ scol)
{
    int b = blockIdx.x;
    int k = b % KK;
    int g = (b / KK) % 2;
    int l = b / (2 * KK);
    int d = threadIdx.x;
    const float* Wp = Wh + ((size_t)((l * 3 + g) * KK + k)) * DD * DD;
    float s = 0.f;
    for (int r = 0; r < DD; ++r) s += Wp[r * DD + d];
    scol[((size_t)((l * 2 + g) * KK + k)) * DD + d] = s;
}

// ===================== dense (N,D) propagation: out = alpha*L_hat@x + beta*prev =====================
// one wave (64 lanes) per node, each lane owns 2 columns (float2)
__global__ __launch_bounds__(256) void prop_mat(
    const int* __restrict__ rp, const int* __restrict__ ss, const float* __restrict__ sw,
    const float* __restrict__ x, const float* __restrict__ prev,
    float* __restrict__ out, float alpha, float beta)
{
    int node = blockIdx.x * 4 + (threadIdx.x >> 6);
    if (node >= NN) return;
    int lane = threadIdx.x & 63;
    int c = lane * 2;
    float ax = 0.f, ay = 0.f;
    int e0 = rp[node], e1 = rp[node + 1];
    for (int e = e0; e < e1; ++e) {
        int s = ss[e];
        float w = sw[e];
        float2 xr = *(const float2*)(x + (size_t)s * DD + c);
        ax += w * xr.x;
        ay += w * xr.y;
    }
    float px = 0.f, py = 0.f;
    if (beta != 0.f && prev) {
        float2 pv = *(const float2*)(prev + (size_t)node * DD + c);
        px = pv.x; py = pv.y;
    }
    float2 o;
    o.x = alpha * ax + beta * px;
    o.y = alpha * ay + beta * py;
    *(float2*)(out + (size_t)node * DD + c) = o;
}

// ===================== fused Chebyshev matmul =====================
// out(g) = [accumulate? out(g):0] + sum_{k=0..4} T_k @ W(g,k)
// W(g,k) = Wbase + g*gate_stride + k*D*D ; out(g) = outbase + g*out_stride
// block: 256 threads, tile 64 rows x 128 cols; thread = (tx 0..15: 8 cols, ty 0..15: 4 rows)
#define TM 64
#define TSTR 132

__global__ __launch_bounds__(256) void cheb_matmul(
    const float* __restrict__ T0, const float* __restrict__ T1,
    const float* __restrict__ T2, const float* __restrict__ T3,
    const float* __restrict__ T4,
    const float* __restrict__ Wbase, int gate_stride,
    float* __restrict__ outbase, size_t out_stride,
    int accumulate)
{
    __shared__ float Tt[TM * TSTR];
    __shared__ float Wc[32 * 128];
    const int g = blockIdx.y;
    const int r0 = blockIdx.x * TM;
    const int tid = threadIdx.x;
    const int tx = tid & 15;
    const int ty = tid >> 4;
    const float* Ws = Wbase + (size_t)g * gate_stride;

    float acc[4][8];
#pragma unroll
    for (int r = 0; r < 4; ++r)
#pragma unroll
        for (int cc = 0; cc < 8; ++cc) acc[r][cc] = 0.f;

    const float* Ts[5] = {T0, T1, T2, T3, T4};
#pragma unroll
    for (int k = 0; k < KK; ++k) {
        const float* Tk = Ts[k];
        const float* Wk = Ws + (size_t)k * DD * DD;
        __syncthreads();
        // stage T tile: 4 threads/row, 32 floats each
        {
            int row = tid >> 2;
            int seg = (tid & 3) * 32;
            int grow = r0 + row;
#pragma unroll
            for (int j = 0; j < 8; ++j) {
                float4 v;
                if (grow < NN) v = *(const float4*)(Tk + (size_t)grow * DD + seg + j * 4);
                else { v.x = 0.f; v.y = 0.f; v.z = 0.f; v.w = 0.f; }
                *(float4*)(&Tt[row * TSTR + seg + j * 4]) = v;
            }
        }
#pragma unroll
        for (int dc = 0; dc < 4; ++dc) {
            if (dc) __syncthreads();
            // stage W rows dc*32..+31 : 8 threads/row, 16 floats each
            {
                int row = tid >> 3;
                int seg = (tid & 7) * 16;
#pragma unroll
                for (int j = 0; j < 4; ++j) {
                    *(float4*)(&Wc[row * 128 + seg + j * 4]) =
                        *(const float4*)(Wk + (size_t)(dc * 32 + row) * DD + seg + j * 4);
                }
            }
            __syncthreads();
#pragma unroll
            for (int d = 0; d < 32; ++d) {
                int dg = dc * 32 + d;
                float4 wa = *(float4*)(&Wc[d * 128 + tx * 8]);
                float4 wb = *(float4*)(&Wc[d * 128 + tx * 8 + 4]);
#pragma unroll
                for (int r = 0; r < 4; ++r) {
                    float tv = Tt[(ty * 4 + r) * TSTR + dg];
                    acc[r][0] += tv * wa.x; acc[r][1] += tv * wa.y;
                    acc[r][2] += tv * wa.z; acc[r][3] += tv * wa.w;
                    acc[r][4] += tv * wb.x; acc[r][5] += tv * wb.y;
                    acc[r][6] += tv * wb.z; acc[r][7] += tv * wb.w;
                }
            }
        }
    }

    float* outp = outbase + (size_t)g * out_stride;
#pragma unroll
    for (int r = 0; r < 4; ++r) {
        int grow = r0 + ty * 4 + r;
        if (grow < NN) {
            float* op = outp + (size_t)grow * DD + tx * 8;
            if (accumulate) {
#pragma unroll
                for (int cc = 0; cc < 8; ++cc) op[cc] += acc[r][cc];
            } else {
                float4 va, vb;
                va.x = acc[r][0]; va.y = acc[r][1]; va.z = acc[r][2]; va.w = acc[r][3];
                vb.x = acc[r][4]; vb.y = acc[r][5]; vb.z = acc[r][6]; vb.w = acc[r][7];
                *(float4*)(op) = va;
                *(float4*)(op + 4) = vb;
            }
        }
    }
}

// ===================== gate kernels =====================
// Z = sigmoid(Xz + bx0 + bh0 + sum_k t_k*scolZ_k) ; R likewise; in-place into Xz/Xr
__global__ __launch_bounds__(256) void gate_zr_kernel(
    float* __restrict__ Xz, float* __restrict__ Xr,
    const float* __restrict__ tvec, const float* __restrict__ scol,
    const float* __restrict__ bx, const float* __restrict__ bh, int l)
{
    int idx = blockIdx.x * blockDim.x + threadIdx.x;
    if (idx >= NN * DD) return;
    int i = idx >> 7;
    int d = idx & 127;
    float t1 = tvec[i], t2 = tvec[NN + i], t3 = tvec[2 * NN + i], t4 = tvec[3 * NN + i];

    const float* s0 = scol + (size_t)((l * 2 + 0) * KK) * DD;
    float hz = s0[d] + t1 * s0[DD + d] + t2 * s0[2 * DD + d] + t3 * s0[3 * DD + d] + t4 * s0[4 * DD + d];
    float z = Xz[idx] + bx[(l * 3 + 0) * DD + d] + bh[(l * 3 + 0) * DD + d] + hz;
    Xz[idx] = 1.f / (1.f + expf(-z));

    const float* s1 = scol + (size_t)((l * 2 + 1) * KK) * DD;
    float hr = s1[d] + t1 * s1[DD + d] + t2 * s1[2 * DD + d] + t3 * s1[3 * DD + d] + t4 * s1[4 * DD + d];
    float r = Xr[idx] + bx[(l * 3 + 1) * DD + d] + bh[(l * 3 + 1) * DD + d] + hr;
    Xr[idx] = 1.f / (1.f + expf(-r));
}

// Ht = tanh(Xh + bx2 + bh2); out = relu(Z + (1-Z)*Ht)
__global__ __launch_bounds__(256) void gate_final_kernel(
    const float* __restrict__ Xz, const float* __restrict__ Xh,
    const float* __restrict__ bx, const float* __restrict__ bh, int l,
    float* __restrict__ out)
{
    int idx = blockIdx.x * blockDim.x + threadIdx.x;
    if (idx >= NN * DD) return;
    int d = idx & 127;
    float ht = tanhf(Xh[idx] + bx[(l * 3 + 2) * DD + d] + bh[(l * 3 + 2) * DD + d]);
    float z = Xz[idx];
    float hn = z + (1.f - z) * ht;
    out[idx] = hn > 0.f ? hn : 0.f;
}

// ===================== host orchestration =====================

extern "C" void kernel_launch(void* const* d_in, const int* in_sizes, int n_in,
                              void* d_out, int out_size, void* d_ws, size_t ws_size,
                              hipStream_t stream)
{
    const int*   ei  = (const int*)d_in[0];
    const float* ew  = (const float*)d_in[1];
    const float* emb = (const float*)d_in[2];
    const float* Wx  = (const float*)d_in[3];
    const float* bx  = (const float*)d_in[4];
    const float* Wh  = (const float*)d_in[5];
    const float* bh  = (const float*)d_in[6];
    float* out = (float*)d_out;

    const int* src = ei;
    const int* dst = ei + EE;

    char* ws = (char*)d_ws;
    size_t off = 0;
    auto alloc = [&](size_t nbytes) -> char* {
        char* p = ws + off;
        off = (off + nbytes + 255) & ~(size_t)255;
        return p;
    };
    float* deg     = (float*)alloc((size_t)NN * 4);
    float* dinv    = (float*)alloc((size_t)NN * 4);
    int*   hist    = (int*)alloc((size_t)(NN + 1) * 4);
    int*   row_ptr = (int*)alloc((size_t)(NN + 1) * 4);
    int*   fill    = (int*)alloc((size_t)(NN + 1) * 4);
    int*   src_srt = (int*)alloc((size_t)EE * 4);
    float* w_srt   = (float*)alloc((size_t)EE * 4);
    float* tvec    = (float*)alloc((size_t)4 * NN * 4);
    float* scol    = (float*)alloc((size_t)LL * 2 * KK * DD * 4);
    float* X       = (float*)alloc((size_t)3 * NN * DD * 4);  // Xz,Xr,Xh
    float* Tb      = (float*)alloc((size_t)4 * NN * DD * 4);  // T1..T4
    (void)ws_size; (void)in_sizes; (void)n_in; (void)out_size;

    float* Xz = X;
    float* Xr = X + (size_t)NN * DD;
    float* Xh = X + (size_t)2 * NN * DD;
    float* T1 = Tb;
    float* T2 = Tb + (size_t)NN * DD;
    float* T3 = Tb + (size_t)2 * NN * DD;
    float* T4 = Tb + (size_t)3 * NN * DD;

    const int EG = (EE + 255) / 256;
    const int NG = (NN + 255) / 256;
    const int PG = (NN + 3) / 4;
    const int ELG = (NN * DD + 255) / 256;
    const int MMG = (NN + TM - 1) / TM;

    hipMemsetAsync(deg, 0, (size_t)NN * 4, stream);
    hipMemsetAsync(hist, 0, (size_t)(NN + 1) * 4, stream);

    edge_pass1<<<EG, 256, 0, stream>>>(src, dst, ew, deg, hist);
    dinv_kernel<<<NG, 256, 0, stream>>>(deg, dinv);
    scan_kernel<<<1, 1024, 0, stream>>>(hist, row_ptr);
    copy_fill<<<NG, 256, 0, stream>>>(row_ptr, fill);
    edge_scatter<<<EG, 256, 0, stream>>>(src, dst, ew, dinv, fill, src_srt, w_srt);

    // scalar Chebyshev vectors t1..t4 (t0 = ones, implicit)
    float* t1 = tvec;
    float* t2 = tvec + NN;
    float* t3 = tvec + 2 * NN;
    float* t4 = tvec + 3 * NN;
    propv_kernel<<<NG, 256, 0, stream>>>(row_ptr, src_srt, w_srt, nullptr, nullptr, t1, 1.f,  0.f, 1, 0);
    propv_kernel<<<NG, 256, 0, stream>>>(row_ptr, src_srt, w_srt, t1, nullptr,      t2, 2.f, -1.f, 0, 1);
    propv_kernel<<<NG, 256, 0, stream>>>(row_ptr, src_srt, w_srt, t2, t1,           t3, 2.f, -1.f, 0, 0);
    propv_kernel<<<NG, 256, 0, stream>>>(row_ptr, src_srt, w_srt, t3, t2,           t4, 2.f, -1.f, 0, 0);

    colsum_kernel<<<LL * 2 * KK, 128, 0, stream>>>(Wh, scol);

    const float* x_in = emb;
    for (int l = 0; l < LL; ++l) {
        // Chebyshev basis of x
        prop_mat<<<PG, 256, 0, stream>>>(row_ptr, src_srt, w_srt, x_in, nullptr, T1, 1.f,  0.f);
        prop_mat<<<PG, 256, 0, stream>>>(row_ptr, src_srt, w_srt, T1,   x_in,    T2, 2.f, -1.f);
        prop_mat<<<PG, 256, 0, stream>>>(row_ptr, src_srt, w_srt, T2,   T1,      T3, 2.f, -1.f);
        prop_mat<<<PG, 256, 0, stream>>>(row_ptr, src_srt, w_srt, T3,   T2,      T4, 2.f, -1.f);

        // Xg = sum_k T_k @ Wx[l,g,k] for g=0,1,2
        dim3 g3(MMG, 3);
        cheb_matmul<<<g3, 256, 0, stream>>>(x_in, T1, T2, T3, T4,
                                            Wx + (size_t)l * 3 * KK * DD * DD, KK * DD * DD,
                                            Xz, (size_t)NN * DD, 0);

        // Z, R (adds the rank-K ones-side cheb + biases), in place
        gate_zr_kernel<<<ELG, 256, 0, stream>>>(Xz, Xr, tvec, scol, bx, bh, l);

        // Chebyshev basis of R (H*R == R since H == ones)
        prop_mat<<<PG, 256, 0, stream>>>(row_ptr, src_srt, w_srt, Xr, nullptr, T1, 1.f,  0.f);
        prop_mat<<<PG, 256, 0, stream>>>(row_ptr, src_srt, w_srt, T1, Xr,      T2, 2.f, -1.f);
        prop_mat<<<PG, 256, 0, stream>>>(row_ptr, src_srt, w_srt, T2, T1,      T3, 2.f, -1.f);
        prop_mat<<<PG, 256, 0, stream>>>(row_ptr, src_srt, w_srt, T3, T2,      T4, 2.f, -1.f);

        // Xh += sum_k TR_k @ Wh[l,2,k]
        dim3 g1(MMG, 1);
        cheb_matmul<<<g1, 256, 0, stream>>>(Xr, T1, T2, T3, T4,
                                            Wh + (size_t)(l * 3 + 2) * KK * DD * DD, 0,
                                            Xh, 0, 1);

        // h = relu(Z + (1-Z)*tanh(Xh + biases)) -> out (used as x for next layer)
        gate_final_kernel<<<ELG, 256, 0, stream>>>(Xz, Xh, bx, bh, l, out);
        x_in = out;
    }
}

// Round 3
// 1569.444 us; speedup vs baseline: 1.5126x; 1.5126x over previous
//
#include <hip/hip_runtime.h>
#include <math.h>

#define NN 50000
#define EE 500000
#define DD 128
#define KK 5
#define LL 2

typedef __bf16 bf16x8 __attribute__((ext_vector_type(8)));
typedef float f32x4 __attribute__((ext_vector_type(4)));

union BfU { __bf16 b; ushort u; };

// ===================== graph preprocessing =====================

__global__ __launch_bounds__(256) void edge_pass1(
    const int* __restrict__ src, const int* __restrict__ dst,
    const float* __restrict__ ew,
    float* __restrict__ deg, int* __restrict__ hist)
{
    int e = blockIdx.x * blockDim.x + threadIdx.x;
    if (e >= EE) return;
    atomicAdd(&deg[src[e]], ew[e]);
    atomicAdd(&hist[dst[e]], 1);
}

__global__ __launch_bounds__(256) void dinv_kernel(
    const float* __restrict__ deg, float* __restrict__ dinv)
{
    int i = blockIdx.x * blockDim.x + threadIdx.x;
    if (i >= NN) return;
    float d = deg[i];
    dinv[i] = (d > 0.f) ? (1.f / sqrtf(d)) : 0.f;
}

__global__ __launch_bounds__(1024) void scan_kernel(
    const int* __restrict__ hist, int* __restrict__ row_ptr)
{
    __shared__ int buf[1024];
    __shared__ int carry;
    int tid = threadIdx.x;
    if (tid == 0) { carry = 0; row_ptr[0] = 0; }
    __syncthreads();
    for (int base = 0; base < NN; base += 1024) {
        int i = base + tid;
        int v = (i < NN) ? hist[i] : 0;
        buf[tid] = v;
        __syncthreads();
        for (int off = 1; off < 1024; off <<= 1) {
            int t = (tid >= off) ? buf[tid - off] : 0;
            __syncthreads();
            buf[tid] += t;
            __syncthreads();
        }
        int incl = buf[tid] + carry;
        if (i < NN) row_ptr[i + 1] = incl;
        __syncthreads();
        if (tid == 1023) carry = incl;
        __syncthreads();
    }
}

__global__ __launch_bounds__(256) void copy_fill(
    const int* __restrict__ row_ptr, int* __restrict__ fill)
{
    int i = blockIdx.x * blockDim.x + threadIdx.x;
    if (i < NN) fill[i] = row_ptr[i];
}

__global__ __launch_bounds__(256) void edge_scatter(
    const int* __restrict__ src, const int* __restrict__ dst,
    const float* __restrict__ ew, const float* __restrict__ dinv,
    int* __restrict__ fill,
    int* __restrict__ src_srt, float* __restrict__ w_srt)
{
    int e = blockIdx.x * blockDim.x + threadIdx.x;
    if (e >= EE) return;
    int s = src[e], t = dst[e];
    float w = -dinv[s] * ew[e] * dinv[t];
    int pos = atomicAdd(&fill[t], 1);
    src_srt[pos] = s;
    w_srt[pos] = w;
}

// ===================== scalar Chebyshev vectors (for H = ones) =====================
__global__ __launch_bounds__(256) void propv_kernel(
    const int* __restrict__ rp, const int* __restrict__ ss, const float* __restrict__ sw,
    const float* __restrict__ tin, const float* __restrict__ tprev, float* __restrict__ tout,
    float alpha, float beta, int ones_in, int ones_prev)
{
    int i = blockIdx.x * blockDim.x + threadIdx.x;
    if (i >= NN) return;
    float acc = 0.f;
    int e0 = rp[i], e1 = rp[i + 1];
    for (int e = e0; e < e1; ++e) {
        float tv = ones_in ? 1.f : tin[ss[e]];
        acc += sw[e] * tv;
    }
    float pv = ones_prev ? 1.f : (tprev ? tprev[i] : 0.f);
    tout[i] = alpha * acc + beta * pv;
}

// colsum of Wh[l, g(0..1), k] -> scol[(l*2+g)*K + k][d]
__global__ __launch_bounds__(128) void colsum_kernel(
    const float* __restrict__ Wh, float* __restrict__ scol)
{
    int b = blockIdx.x;
    int k = b % KK;
    int g = (b / KK) % 2;
    int l = b / (2 * KK);
    int d = threadIdx.x;
    const float* Wp = Wh + ((size_t)((l * 3 + g) * KK + k)) * DD * DD;
    float s = 0.f;
    for (int r = 0; r < DD; ++r) s += Wp[r * DD + d];
    scol[((size_t)((l * 2 + g) * KK + k)) * DD + d] = s;
}

// ===================== weight split: fp32 -> (hi,lo) bf16, transposed + pre-swizzled ==
// dst tile t: [hi: 128x128 bf16 swizzled][lo: 128x128 bf16 swizzled]  (64KB per tile)
// element (dout=rb, din=c) at byte (rb*256 + ((c*2) ^ ((rb&7)<<4)))
// mode 0: src tile = t (Wx: [L][3][K] tiles); mode 1: src tile = ((t/K)*3+2)*K + t%K (Wh gate2)
__global__ __launch_bounds__(256) void wconv_split(
    const float* __restrict__ W, ushort* __restrict__ out, int mode)
{
    int t = blockIdx.x;
    int st = (mode == 0) ? t : ((t / KK) * 3 + 2) * KK + (t % KK);
    const float* Wp = W + (size_t)st * DD * DD;
    ushort* hi = out + (size_t)t * DD * DD * 2;
    ushort* lo = hi + DD * DD;
    for (int idx = threadIdx.x; idx < DD * DD; idx += 256) {
        int rb = idx >> 7, c = idx & 127;
        float w = Wp[c * DD + rb];          // transpose: [dout][din] from [din][dout]
        BfU h, l2;
        h.b = (__bf16)w;
        float r = w - (float)h.b;
        l2.b = (__bf16)r;
        int byte = rb * 256 + (((c * 2) ^ ((rb & 7) << 4)));
        *(ushort*)((char*)hi + byte) = h.u;
        *(ushort*)((char*)lo + byte) = l2.u;
    }
}

// ===================== dense (N,D) propagation: out = alpha*L_hat@x + beta*prev ===
__global__ __launch_bounds__(256) void prop_mat(
    const int* __restrict__ rp, const int* __restrict__ ss, const float* __restrict__ sw,
    const float* __restrict__ x, const float* __restrict__ prev,
    float* __restrict__ out, float alpha, float beta)
{
    int node = blockIdx.x * 4 + (threadIdx.x >> 6);
    if (node >= NN) return;
    int lane = threadIdx.x & 63;
    int c = lane * 2;
    float ax = 0.f, ay = 0.f;
    int e0 = rp[node], e1 = rp[node + 1];
    for (int e = e0; e < e1; ++e) {
        int s = ss[e];
        float w = sw[e];
        float2 xr = *(const float2*)(x + (size_t)s * DD + c);
        ax += w * xr.x;
        ay += w * xr.y;
    }
    float px = 0.f, py = 0.f;
    if (beta != 0.f && prev) {
        float2 pv = *(const float2*)(prev + (size_t)node * DD + c);
        px = pv.x; py = pv.y;
    }
    float2 o;
    o.x = alpha * ax + beta * px;
    o.y = alpha * ay + beta * py;
    *(float2*)(out + (size_t)node * DD + c) = o;
}

// ===================== 3-pass split-bf16 MFMA Chebyshev matmul =====================
// out(g) = [accumulate? out(g):0] + sum_k T_k @ W(g,k), fp32-accurate via
// Ahi*Bhi + Alo*Bhi + Ahi*Blo. A read fp32 from global, split in-register.
// W tiles pre-split/pre-swizzled by wconv_split. Block 256 thr, tile 128x128.
__global__ __launch_bounds__(256) void cheb_mm_mfma(
    const float* __restrict__ T0, const float* __restrict__ T1,
    const float* __restrict__ T2, const float* __restrict__ T3,
    const float* __restrict__ T4,
    const ushort* __restrict__ Wt, int gate_stride,   // ushorts between gates
    float* __restrict__ outbase, size_t out_stride, int accumulate)
{
    __shared__ ushort Bs[DD * DD * 2];  // 64KB: hi plane + lo plane
    const int tid = threadIdx.x;
    const int lane = tid & 63;
    const int wid = tid >> 6;
    const int lr = lane & 15;
    const int lk = lane >> 4;
    const int g = blockIdx.y;
    const int r0 = blockIdx.x * 128;
    const ushort* Wg = Wt + (size_t)g * gate_stride;
    const float* Ts[5] = {T0, T1, T2, T3, T4};

    f32x4 acc[2][8];
#pragma unroll
    for (int fr = 0; fr < 2; ++fr)
#pragma unroll
        for (int fc = 0; fc < 8; ++fc)
            acc[fr][fc] = (f32x4){0.f, 0.f, 0.f, 0.f};

    int rowg0 = r0 + wid * 32 + lr;
    int rowg1 = rowg0 + 16;
    bool ok0 = rowg0 < NN;
    bool ok1 = rowg1 < NN;

#pragma unroll
    for (int k = 0; k < KK; ++k) {
        const float* Tk = Ts[k];
        const ushort* Bg = Wg + (size_t)k * (DD * DD * 2);
        __syncthreads();
        // stage 64KB linear (global layout already swizzled)
#pragma unroll
        for (int i = 0; i < 16; ++i) {
            int off = i * 4096 + tid * 16;
            uint4 v = *(const uint4*)((const char*)Bg + off);
            *(uint4*)((char*)Bs + off) = v;
        }
        // A: fp32 global load + hi/lo split in registers
        bf16x8 ahi[2][4], alo[2][4];
#pragma unroll
        for (int fr = 0; fr < 2; ++fr) {
            int rowg = fr ? rowg1 : rowg0;
            bool ok = fr ? ok1 : ok0;
            const float* rp2 = Tk + (size_t)rowg * DD + lk * 8;
#pragma unroll
            for (int ko = 0; ko < 4; ++ko) {
                float4 f0, f1;
                if (ok) {
                    f0 = *(const float4*)(rp2 + ko * 32);
                    f1 = *(const float4*)(rp2 + ko * 32 + 4);
                } else {
                    f0 = (float4){0.f, 0.f, 0.f, 0.f};
                    f1 = (float4){0.f, 0.f, 0.f, 0.f};
                }
                float fa0 = f0.x, fa1 = f0.y, fa2 = f0.z, fa3 = f0.w;
                float fa4 = f1.x, fa5 = f1.y, fa6 = f1.z, fa7 = f1.w;
                bf16x8 h, l;
                h[0] = (__bf16)fa0; h[1] = (__bf16)fa1; h[2] = (__bf16)fa2; h[3] = (__bf16)fa3;
                h[4] = (__bf16)fa4; h[5] = (__bf16)fa5; h[6] = (__bf16)fa6; h[7] = (__bf16)fa7;
                l[0] = (__bf16)(fa0 - (float)h[0]); l[1] = (__bf16)(fa1 - (float)h[1]);
                l[2] = (__bf16)(fa2 - (float)h[2]); l[3] = (__bf16)(fa3 - (float)h[3]);
                l[4] = (__bf16)(fa4 - (float)h[4]); l[5] = (__bf16)(fa5 - (float)h[5]);
                l[6] = (__bf16)(fa6 - (float)h[6]); l[7] = (__bf16)(fa7 - (float)h[7]);
                ahi[fr][ko] = h;
                alo[fr][ko] = l;
            }
        }
        __syncthreads();
        // MFMA: 3-pass per (ko, fc)
#pragma unroll
        for (int ko = 0; ko < 4; ++ko) {
            const int cb = ko * 64 + lk * 16;
#pragma unroll
            for (int fc = 0; fc < 8; ++fc) {
                int rb = fc * 16 + lr;
                int byte = (rb * 256 + cb) ^ ((rb & 7) << 4);
                bf16x8 bh = *(const bf16x8*)((const char*)Bs + byte);
                bf16x8 bl = *(const bf16x8*)((const char*)Bs + 32768 + byte);
                acc[0][fc] = __builtin_amdgcn_mfma_f32_16x16x32_bf16(ahi[0][ko], bh, acc[0][fc], 0, 0, 0);
                acc[1][fc] = __builtin_amdgcn_mfma_f32_16x16x32_bf16(ahi[1][ko], bh, acc[1][fc], 0, 0, 0);
                acc[0][fc] = __builtin_amdgcn_mfma_f32_16x16x32_bf16(alo[0][ko], bh, acc[0][fc], 0, 0, 0);
                acc[1][fc] = __builtin_amdgcn_mfma_f32_16x16x32_bf16(alo[1][ko], bh, acc[1][fc], 0, 0, 0);
                acc[0][fc] = __builtin_amdgcn_mfma_f32_16x16x32_bf16(ahi[0][ko], bl, acc[0][fc], 0, 0, 0);
                acc[1][fc] = __builtin_amdgcn_mfma_f32_16x16x32_bf16(ahi[1][ko], bl, acc[1][fc], 0, 0, 0);
            }
        }
    }

    float* outp = outbase + (size_t)g * out_stride;
#pragma unroll
    for (int fr = 0; fr < 2; ++fr) {
#pragma unroll
        for (int j = 0; j < 4; ++j) {
            int grow = r0 + wid * 32 + fr * 16 + lk * 4 + j;
            if (grow < NN) {
#pragma unroll
                for (int fc = 0; fc < 8; ++fc) {
                    int col = fc * 16 + lr;
                    float* p = outp + (size_t)grow * DD + col;
                    float v = acc[fr][fc][j];
                    if (accumulate) *p += v; else *p = v;
                }
            }
        }
    }
}

// ===================== gate kernels =====================
__global__ __launch_bounds__(256) void gate_zr_kernel(
    float* __restrict__ Xz, float* __restrict__ Xr,
    const float* __restrict__ tvec, const float* __restrict__ scol,
    const float* __restrict__ bx, const float* __restrict__ bh, int l)
{
    int idx = blockIdx.x * blockDim.x + threadIdx.x;
    if (idx >= NN * DD) return;
    int i = idx >> 7;
    int d = idx & 127;
    float t1 = tvec[i], t2 = tvec[NN + i], t3 = tvec[2 * NN + i], t4 = tvec[3 * NN + i];

    const float* s0 = scol + (size_t)((l * 2 + 0) * KK) * DD;
    float hz = s0[d] + t1 * s0[DD + d] + t2 * s0[2 * DD + d] + t3 * s0[3 * DD + d] + t4 * s0[4 * DD + d];
    float z = Xz[idx] + bx[(l * 3 + 0) * DD + d] + bh[(l * 3 + 0) * DD + d] + hz;
    Xz[idx] = 1.f / (1.f + expf(-z));

    const float* s1 = scol + (size_t)((l * 2 + 1) * KK) * DD;
    float hr = s1[d] + t1 * s1[DD + d] + t2 * s1[2 * DD + d] + t3 * s1[3 * DD + d] + t4 * s1[4 * DD + d];
    float r = Xr[idx] + bx[(l * 3 + 1) * DD + d] + bh[(l * 3 + 1) * DD + d] + hr;
    Xr[idx] = 1.f / (1.f + expf(-r));
}

__global__ __launch_bounds__(256) void gate_final_kernel(
    const float* __restrict__ Xz, const float* __restrict__ Xh,
    const float* __restrict__ bx, const float* __restrict__ bh, int l,
    float* __restrict__ out)
{
    int idx = blockIdx.x * blockDim.x + threadIdx.x;
    if (idx >= NN * DD) return;
    int d = idx & 127;
    float ht = tanhf(Xh[idx] + bx[(l * 3 + 2) * DD + d] + bh[(l * 3 + 2) * DD + d]);
    float z = Xz[idx];
    float hn = z + (1.f - z) * ht;
    out[idx] = hn > 0.f ? hn : 0.f;
}

// ===================== host orchestration =====================

extern "C" void kernel_launch(void* const* d_in, const int* in_sizes, int n_in,
                              void* d_out, int out_size, void* d_ws, size_t ws_size,
                              hipStream_t stream)
{
    const int*   ei  = (const int*)d_in[0];
    const float* ew  = (const float*)d_in[1];
    const float* emb = (const float*)d_in[2];
    const float* Wx  = (const float*)d_in[3];
    const float* bx  = (const float*)d_in[4];
    const float* Wh  = (const float*)d_in[5];
    const float* bh  = (const float*)d_in[6];
    float* out = (float*)d_out;

    const int* src = ei;
    const int* dst = ei + EE;

    char* ws = (char*)d_ws;
    size_t off = 0;
    auto alloc = [&](size_t nbytes) -> char* {
        char* p = ws + off;
        off = (off + nbytes + 255) & ~(size_t)255;
        return p;
    };
    float*  deg     = (float*)alloc((size_t)NN * 4);
    float*  dinv    = (float*)alloc((size_t)NN * 4);
    int*    hist    = (int*)alloc((size_t)(NN + 1) * 4);
    int*    row_ptr = (int*)alloc((size_t)(NN + 1) * 4);
    int*    fill    = (int*)alloc((size_t)(NN + 1) * 4);
    int*    src_srt = (int*)alloc((size_t)EE * 4);
    float*  w_srt   = (float*)alloc((size_t)EE * 4);
    float*  tvec    = (float*)alloc((size_t)4 * NN * 4);
    float*  scol    = (float*)alloc((size_t)LL * 2 * KK * DD * 4);
    float*  X       = (float*)alloc((size_t)3 * NN * DD * 4);   // Xz,Xr,Xh fp32
    float*  Tf      = (float*)alloc((size_t)4 * NN * DD * 4);   // T1..T4 fp32
    ushort* WxT     = (ushort*)alloc((size_t)LL * 3 * KK * DD * DD * 2 * 2); // hi+lo
    ushort* WhT2    = (ushort*)alloc((size_t)LL * KK * DD * DD * 2 * 2);     // hi+lo
    (void)ws_size; (void)in_sizes; (void)n_in; (void)out_size;

    float* Xz = X;
    float* Xr = X + (size_t)NN * DD;
    float* Xh = X + (size_t)2 * NN * DD;
    float* T1 = Tf;
    float* T2 = Tf + (size_t)NN * DD;
    float* T3 = Tf + (size_t)2 * NN * DD;
    float* T4 = Tf + (size_t)3 * NN * DD;

    const int EG = (EE + 255) / 256;
    const int NG = (NN + 255) / 256;
    const int PG = (NN + 3) / 4;
    const int ELG = (NN * DD + 255) / 256;
    const int MMG = (NN + 127) / 128;
    const int GATE_STRIDE = KK * DD * DD * 2;  // ushorts per gate (hi+lo per k, K tiles)

    hipMemsetAsync(deg, 0, (size_t)NN * 4, stream);
    hipMemsetAsync(hist, 0, (size_t)(NN + 1) * 4, stream);

    edge_pass1<<<EG, 256, 0, stream>>>(src, dst, ew, deg, hist);
    dinv_kernel<<<NG, 256, 0, stream>>>(deg, dinv);
    scan_kernel<<<1, 1024, 0, stream>>>(hist, row_ptr);
    copy_fill<<<NG, 256, 0, stream>>>(row_ptr, fill);
    edge_scatter<<<EG, 256, 0, stream>>>(src, dst, ew, dinv, fill, src_srt, w_srt);

    // scalar Chebyshev vectors t1..t4 (t0 = ones, implicit)
    float* t1 = tvec;
    float* t2 = tvec + NN;
    float* t3 = tvec + 2 * NN;
    float* t4 = tvec + 3 * NN;
    propv_kernel<<<NG, 256, 0, stream>>>(row_ptr, src_srt, w_srt, nullptr, nullptr, t1, 1.f,  0.f, 1, 0);
    propv_kernel<<<NG, 256, 0, stream>>>(row_ptr, src_srt, w_srt, t1, nullptr,      t2, 2.f, -1.f, 0, 1);
    propv_kernel<<<NG, 256, 0, stream>>>(row_ptr, src_srt, w_srt, t2, t1,           t3, 2.f, -1.f, 0, 0);
    propv_kernel<<<NG, 256, 0, stream>>>(row_ptr, src_srt, w_srt, t3, t2,           t4, 2.f, -1.f, 0, 0);

    colsum_kernel<<<LL * 2 * KK, 128, 0, stream>>>(Wh, scol);

    // weights -> hi/lo bf16, transposed + pre-swizzled
    wconv_split<<<LL * 3 * KK, 256, 0, stream>>>(Wx, WxT, 0);
    wconv_split<<<LL * KK, 256, 0, stream>>>(Wh, WhT2, 1);

    const float* x_in = emb;
    for (int l = 0; l < LL; ++l) {
        // Chebyshev basis of x (fp32)
        prop_mat<<<PG, 256, 0, stream>>>(row_ptr, src_srt, w_srt, x_in, nullptr, T1, 1.f,  0.f);
        prop_mat<<<PG, 256, 0, stream>>>(row_ptr, src_srt, w_srt, T1,   x_in,    T2, 2.f, -1.f);
        prop_mat<<<PG, 256, 0, stream>>>(row_ptr, src_srt, w_srt, T2,   T1,      T3, 2.f, -1.f);
        prop_mat<<<PG, 256, 0, stream>>>(row_ptr, src_srt, w_srt, T3,   T2,      T4, 2.f, -1.f);

        // Xg = sum_k T_k @ Wx[l,g,k], g=0..2 (3-pass split MFMA)
        dim3 g3(MMG, 3);
        cheb_mm_mfma<<<g3, 256, 0, stream>>>(x_in, T1, T2, T3, T4,
                                             WxT + (size_t)l * 3 * GATE_STRIDE, GATE_STRIDE,
                                             Xz, (size_t)NN * DD, 0);

        // Z, R (rank-K ones-side cheb + biases), in place
        gate_zr_kernel<<<ELG, 256, 0, stream>>>(Xz, Xr, tvec, scol, bx, bh, l);

        // Chebyshev basis of R (H*R == R since H == ones)
        prop_mat<<<PG, 256, 0, stream>>>(row_ptr, src_srt, w_srt, Xr, nullptr, T1, 1.f,  0.f);
        prop_mat<<<PG, 256, 0, stream>>>(row_ptr, src_srt, w_srt, T1, Xr,      T2, 2.f, -1.f);
        prop_mat<<<PG, 256, 0, stream>>>(row_ptr, src_srt, w_srt, T2, T1,      T3, 2.f, -1.f);
        prop_mat<<<PG, 256, 0, stream>>>(row_ptr, src_srt, w_srt, T3, T2,      T4, 2.f, -1.f);

        // Xh += sum_k TR_k @ Wh[l,2,k]
        dim3 g1(MMG, 1);
        cheb_mm_mfma<<<g1, 256, 0, stream>>>(Xr, T1, T2, T3, T4,
                                             WhT2 + (size_t)l * GATE_STRIDE, 0,
                                             Xh, 0, 1);

        // h = relu(Z + (1-Z)*tanh(Xh + biases)) -> out (x for next layer)
        gate_final_kernel<<<ELG, 256, 0, stream>>>(Xz, Xh, bx, bh, l, out);
        x_in = out;
    }
}

// Round 4
// 1223.360 us; speedup vs baseline: 1.9404x; 1.2829x over previous
//
#include <hip/hip_runtime.h>
#include <math.h>

#define NN 50000
#define EE 500000
#define DD 128
#define KK 5
#define LL 2

typedef __bf16 bf16x8 __attribute__((ext_vector_type(8)));
typedef float f32x4 __attribute__((ext_vector_type(4)));

union BfU { __bf16 b; ushort u; };

// ===================== graph preprocessing =====================

__global__ __launch_bounds__(256) void edge_pass1(
    const int* __restrict__ src, const int* __restrict__ dst,
    const float* __restrict__ ew,
    float* __restrict__ deg, int* __restrict__ hist)
{
    int e = blockIdx.x * blockDim.x + threadIdx.x;
    if (e >= EE) return;
    atomicAdd(&deg[src[e]], ew[e]);
    atomicAdd(&hist[dst[e]], 1);
}

__global__ __launch_bounds__(256) void dinv_kernel(
    const float* __restrict__ deg, float* __restrict__ dinv)
{
    int i = blockIdx.x * blockDim.x + threadIdx.x;
    if (i >= NN) return;
    float d = deg[i];
    dinv[i] = (d > 0.f) ? (1.f / sqrtf(d)) : 0.f;
}

__global__ __launch_bounds__(1024) void scan_kernel(
    const int* __restrict__ hist, int* __restrict__ row_ptr)
{
    __shared__ int buf[1024];
    __shared__ int carry;
    int tid = threadIdx.x;
    if (tid == 0) { carry = 0; row_ptr[0] = 0; }
    __syncthreads();
    for (int base = 0; base < NN; base += 1024) {
        int i = base + tid;
        int v = (i < NN) ? hist[i] : 0;
        buf[tid] = v;
        __syncthreads();
        for (int off = 1; off < 1024; off <<= 1) {
            int t = (tid >= off) ? buf[tid - off] : 0;
            __syncthreads();
            buf[tid] += t;
            __syncthreads();
        }
        int incl = buf[tid] + carry;
        if (i < NN) row_ptr[i + 1] = incl;
        __syncthreads();
        if (tid == 1023) carry = incl;
        __syncthreads();
    }
}

__global__ __launch_bounds__(256) void copy_fill(
    const int* __restrict__ row_ptr, int* __restrict__ fill)
{
    int i = blockIdx.x * blockDim.x + threadIdx.x;
    if (i < NN) fill[i] = row_ptr[i];
}

__global__ __launch_bounds__(256) void edge_scatter(
    const int* __restrict__ src, const int* __restrict__ dst,
    const float* __restrict__ ew, const float* __restrict__ dinv,
    int* __restrict__ fill,
    int* __restrict__ src_srt, float* __restrict__ w_srt)
{
    int e = blockIdx.x * blockDim.x + threadIdx.x;
    if (e >= EE) return;
    int s = src[e], t = dst[e];
    float w = -dinv[s] * ew[e] * dinv[t];
    int pos = atomicAdd(&fill[t], 1);
    src_srt[pos] = s;
    w_srt[pos] = w;
}

// ===================== scalar Chebyshev vectors (for H = ones) =====================
__global__ __launch_bounds__(256) void propv_kernel(
    const int* __restrict__ rp, const int* __restrict__ ss, const float* __restrict__ sw,
    const float* __restrict__ tin, const float* __restrict__ tprev, float* __restrict__ tout,
    float alpha, float beta, int ones_in, int ones_prev)
{
    int i = blockIdx.x * blockDim.x + threadIdx.x;
    if (i >= NN) return;
    float acc = 0.f;
    int e0 = rp[i], e1 = rp[i + 1];
    int e = e0;
    for (; e + 4 <= e1; e += 4) {
        float t0 = ones_in ? 1.f : tin[ss[e]];
        float t1v = ones_in ? 1.f : tin[ss[e + 1]];
        float t2v = ones_in ? 1.f : tin[ss[e + 2]];
        float t3v = ones_in ? 1.f : tin[ss[e + 3]];
        acc += sw[e] * t0 + sw[e + 1] * t1v + sw[e + 2] * t2v + sw[e + 3] * t3v;
    }
    for (; e < e1; ++e) {
        float tv = ones_in ? 1.f : tin[ss[e]];
        acc += sw[e] * tv;
    }
    float pv = ones_prev ? 1.f : (tprev ? tprev[i] : 0.f);
    tout[i] = alpha * acc + beta * pv;
}

// colsum of Wh[l, g(0..1), k] -> scol[(l*2+g)*K + k][d]
__global__ __launch_bounds__(128) void colsum_kernel(
    const float* __restrict__ Wh, float* __restrict__ scol)
{
    int b = blockIdx.x;
    int k = b % KK;
    int g = (b / KK) % 2;
    int l = b / (2 * KK);
    int d = threadIdx.x;
    const float* Wp = Wh + ((size_t)((l * 3 + g) * KK + k)) * DD * DD;
    float s = 0.f;
    for (int r = 0; r < DD; ++r) s += Wp[r * DD + d];
    scol[((size_t)((l * 2 + g) * KK + k)) * DD + d] = s;
}

// ===================== weight split: fp32 -> (hi,lo) bf16, transposed + pre-swizzled ==
__global__ __launch_bounds__(256) void wconv_split(
    const float* __restrict__ W, ushort* __restrict__ out, int mode)
{
    int t = blockIdx.x;
    int st = (mode == 0) ? t : ((t / KK) * 3 + 2) * KK + (t % KK);
    const float* Wp = W + (size_t)st * DD * DD;
    ushort* hi = out + (size_t)t * DD * DD * 2;
    ushort* lo = hi + DD * DD;
    for (int idx = threadIdx.x; idx < DD * DD; idx += 256) {
        int rb = idx >> 7, c = idx & 127;
        float w = Wp[c * DD + rb];          // transpose: [dout][din] from [din][dout]
        BfU h, l2;
        h.b = (__bf16)w;
        float r = w - (float)h.b;
        l2.b = (__bf16)r;
        int byte = rb * 256 + (((c * 2) ^ ((rb & 7) << 4)));
        *(ushort*)((char*)hi + byte) = h.u;
        *(ushort*)((char*)lo + byte) = l2.u;
    }
}

// ===================== dense (N,D) propagation: out = alpha*L_hat@x + beta*prev ===
// half-wave (32 lanes) per node, lane owns 4 cols (float4); 4-edge unroll for MLP
__global__ __launch_bounds__(256) void prop_mat(
    const int* __restrict__ rp, const int* __restrict__ ss, const float* __restrict__ sw,
    const float* __restrict__ x, const float* __restrict__ prev,
    float* __restrict__ out, float alpha, float beta)
{
    int node = blockIdx.x * 8 + (threadIdx.x >> 5);
    if (node >= NN) return;
    int lane = threadIdx.x & 31;
    int c = lane * 4;
    float ax = 0.f, ay = 0.f, az = 0.f, aw = 0.f;
    int e0 = rp[node], e1 = rp[node + 1];
    int e = e0;
    for (; e + 4 <= e1; e += 4) {
        int s0 = ss[e], s1 = ss[e + 1], s2 = ss[e + 2], s3 = ss[e + 3];
        float w0 = sw[e], w1 = sw[e + 1], w2 = sw[e + 2], w3 = sw[e + 3];
        float4 r0 = *(const float4*)(x + (size_t)s0 * DD + c);
        float4 r1 = *(const float4*)(x + (size_t)s1 * DD + c);
        float4 r2 = *(const float4*)(x + (size_t)s2 * DD + c);
        float4 r3 = *(const float4*)(x + (size_t)s3 * DD + c);
        ax += w0 * r0.x + w1 * r1.x + w2 * r2.x + w3 * r3.x;
        ay += w0 * r0.y + w1 * r1.y + w2 * r2.y + w3 * r3.y;
        az += w0 * r0.z + w1 * r1.z + w2 * r2.z + w3 * r3.z;
        aw += w0 * r0.w + w1 * r1.w + w2 * r2.w + w3 * r3.w;
    }
    for (; e < e1; ++e) {
        int s = ss[e];
        float w = sw[e];
        float4 r = *(const float4*)(x + (size_t)s * DD + c);
        ax += w * r.x; ay += w * r.y; az += w * r.z; aw += w * r.w;
    }
    float4 o;
    o.x = alpha * ax; o.y = alpha * ay; o.z = alpha * az; o.w = alpha * aw;
    if (beta != 0.f && prev) {
        float4 pv = *(const float4*)(prev + (size_t)node * DD + c);
        o.x += beta * pv.x; o.y += beta * pv.y; o.z += beta * pv.z; o.w += beta * pv.w;
    }
    *(float4*)(out + (size_t)node * DD + c) = o;
}

// ===================== 3-pass split-bf16 MFMA Chebyshev matmul =====================
// out(g) = [accumulate? out(g):0] + sum_k T_k @ W(g,k), fp32-accurate via
// Ahi*Bhi + Alo*Bhi + Ahi*Blo. A read fp32 from global, split in-register.
// 1D grid = ntile*ngates with bijective XCD-chunked swizzle so the ngates
// gate-blocks of one row-tile co-locate on one XCD (share A in L2).
__global__ __launch_bounds__(256) void cheb_mm_mfma(
    const float* __restrict__ T0, const float* __restrict__ T1,
    const float* __restrict__ T2, const float* __restrict__ T3,
    const float* __restrict__ T4,
    const ushort* __restrict__ Wt, int gate_stride,   // ushorts between gates
    float* __restrict__ outbase, size_t out_stride, int accumulate, int ngates)
{
    __shared__ ushort Bs[DD * DD * 2];  // 64KB: hi plane + lo plane

    // XCD-chunked bijective swizzle (m204): consecutive lin ids per XCD chunk
    const int nwg = gridDim.x;
    const int b = blockIdx.x;
    const int xcd = b & 7, idx = b >> 3;
    const int q = nwg >> 3, rr = nwg & 7;
    const int start = (xcd < rr) ? xcd * (q + 1) : rr * (q + 1) + (xcd - rr) * q;
    const int lin = start + idx;
    const int tile = lin / ngates;
    const int g = lin - tile * ngates;

    const int tid = threadIdx.x;
    const int lane = tid & 63;
    const int wid = tid >> 6;
    const int lr = lane & 15;
    const int lk = lane >> 4;
    const int r0 = tile * 128;
    const ushort* Wg = Wt + (size_t)g * gate_stride;
    const float* Ts[5] = {T0, T1, T2, T3, T4};

    f32x4 acc[2][8];
#pragma unroll
    for (int fr = 0; fr < 2; ++fr)
#pragma unroll
        for (int fc = 0; fc < 8; ++fc)
            acc[fr][fc] = (f32x4){0.f, 0.f, 0.f, 0.f};

    int rowg0 = r0 + wid * 32 + lr;
    int rowg1 = rowg0 + 16;
    bool ok0 = rowg0 < NN;
    bool ok1 = rowg1 < NN;

#pragma unroll
    for (int k = 0; k < KK; ++k) {
        const float* Tk = Ts[k];
        const ushort* Bg = Wg + (size_t)k * (DD * DD * 2);
        __syncthreads();
        // stage 64KB linear (global layout already swizzled)
#pragma unroll
        for (int i = 0; i < 16; ++i) {
            int off = i * 4096 + tid * 16;
            uint4 v = *(const uint4*)((const char*)Bg + off);
            *(uint4*)((char*)Bs + off) = v;
        }
        // A: fp32 global load + hi/lo split in registers
        bf16x8 ahi[2][4], alo[2][4];
#pragma unroll
        for (int fr = 0; fr < 2; ++fr) {
            int rowg = fr ? rowg1 : rowg0;
            bool ok = fr ? ok1 : ok0;
            const float* rp2 = Tk + (size_t)rowg * DD + lk * 8;
#pragma unroll
            for (int ko = 0; ko < 4; ++ko) {
                float4 f0, f1;
                if (ok) {
                    f0 = *(const float4*)(rp2 + ko * 32);
                    f1 = *(const float4*)(rp2 + ko * 32 + 4);
                } else {
                    f0 = (float4){0.f, 0.f, 0.f, 0.f};
                    f1 = (float4){0.f, 0.f, 0.f, 0.f};
                }
                float fa0 = f0.x, fa1 = f0.y, fa2 = f0.z, fa3 = f0.w;
                float fa4 = f1.x, fa5 = f1.y, fa6 = f1.z, fa7 = f1.w;
                bf16x8 h, l;
                h[0] = (__bf16)fa0; h[1] = (__bf16)fa1; h[2] = (__bf16)fa2; h[3] = (__bf16)fa3;
                h[4] = (__bf16)fa4; h[5] = (__bf16)fa5; h[6] = (__bf16)fa6; h[7] = (__bf16)fa7;
                l[0] = (__bf16)(fa0 - (float)h[0]); l[1] = (__bf16)(fa1 - (float)h[1]);
                l[2] = (__bf16)(fa2 - (float)h[2]); l[3] = (__bf16)(fa3 - (float)h[3]);
                l[4] = (__bf16)(fa4 - (float)h[4]); l[5] = (__bf16)(fa5 - (float)h[5]);
                l[6] = (__bf16)(fa6 - (float)h[6]); l[7] = (__bf16)(fa7 - (float)h[7]);
                ahi[fr][ko] = h;
                alo[fr][ko] = l;
            }
        }
        __syncthreads();
        // MFMA: 3-pass per (ko, fc)
#pragma unroll
        for (int ko = 0; ko < 4; ++ko) {
            const int cb = ko * 64 + lk * 16;
#pragma unroll
            for (int fc = 0; fc < 8; ++fc) {
                int rb = fc * 16 + lr;
                int byte = (rb * 256 + cb) ^ ((rb & 7) << 4);
                bf16x8 bh = *(const bf16x8*)((const char*)Bs + byte);
                bf16x8 bl = *(const bf16x8*)((const char*)Bs + 32768 + byte);
                acc[0][fc] = __builtin_amdgcn_mfma_f32_16x16x32_bf16(ahi[0][ko], bh, acc[0][fc], 0, 0, 0);
                acc[1][fc] = __builtin_amdgcn_mfma_f32_16x16x32_bf16(ahi[1][ko], bh, acc[1][fc], 0, 0, 0);
                acc[0][fc] = __builtin_amdgcn_mfma_f32_16x16x32_bf16(alo[0][ko], bh, acc[0][fc], 0, 0, 0);
                acc[1][fc] = __builtin_amdgcn_mfma_f32_16x16x32_bf16(alo[1][ko], bh, acc[1][fc], 0, 0, 0);
                acc[0][fc] = __builtin_amdgcn_mfma_f32_16x16x32_bf16(ahi[0][ko], bl, acc[0][fc], 0, 0, 0);
                acc[1][fc] = __builtin_amdgcn_mfma_f32_16x16x32_bf16(ahi[1][ko], bl, acc[1][fc], 0, 0, 0);
            }
        }
    }

    float* outp = outbase + (size_t)g * out_stride;
#pragma unroll
    for (int fr = 0; fr < 2; ++fr) {
#pragma unroll
        for (int j = 0; j < 4; ++j) {
            int grow = r0 + wid * 32 + fr * 16 + lk * 4 + j;
            if (grow < NN) {
#pragma unroll
                for (int fc = 0; fc < 8; ++fc) {
                    int col = fc * 16 + lr;
                    float* p = outp + (size_t)grow * DD + col;
                    float v = acc[fr][fc][j];
                    if (accumulate) *p += v; else *p = v;
                }
            }
        }
    }
}

// ===================== gate kernels =====================
__global__ __launch_bounds__(256) void gate_zr_kernel(
    float* __restrict__ Xz, float* __restrict__ Xr,
    const float* __restrict__ tvec, const float* __restrict__ scol,
    const float* __restrict__ bx, const float* __restrict__ bh, int l)
{
    int idx = blockIdx.x * blockDim.x + threadIdx.x;
    if (idx >= NN * DD) return;
    int i = idx >> 7;
    int d = idx & 127;
    float t1 = tvec[i], t2 = tvec[NN + i], t3 = tvec[2 * NN + i], t4 = tvec[3 * NN + i];

    const float* s0 = scol + (size_t)((l * 2 + 0) * KK) * DD;
    float hz = s0[d] + t1 * s0[DD + d] + t2 * s0[2 * DD + d] + t3 * s0[3 * DD + d] + t4 * s0[4 * DD + d];
    float z = Xz[idx] + bx[(l * 3 + 0) * DD + d] + bh[(l * 3 + 0) * DD + d] + hz;
    Xz[idx] = 1.f / (1.f + expf(-z));

    const float* s1 = scol + (size_t)((l * 2 + 1) * KK) * DD;
    float hr = s1[d] + t1 * s1[DD + d] + t2 * s1[2 * DD + d] + t3 * s1[3 * DD + d] + t4 * s1[4 * DD + d];
    float r = Xr[idx] + bx[(l * 3 + 1) * DD + d] + bh[(l * 3 + 1) * DD + d] + hr;
    Xr[idx] = 1.f / (1.f + expf(-r));
}

__global__ __launch_bounds__(256) void gate_final_kernel(
    const float* __restrict__ Xz, const float* __restrict__ Xh,
    const float* __restrict__ bx, const float* __restrict__ bh, int l,
    float* __restrict__ out)
{
    int idx = blockIdx.x * blockDim.x + threadIdx.x;
    if (idx >= NN * DD) return;
    int d = idx & 127;
    float ht = tanhf(Xh[idx] + bx[(l * 3 + 2) * DD + d] + bh[(l * 3 + 2) * DD + d]);
    float z = Xz[idx];
    float hn = z + (1.f - z) * ht;
    out[idx] = hn > 0.f ? hn : 0.f;
}

// ===================== host orchestration =====================

extern "C" void kernel_launch(void* const* d_in, const int* in_sizes, int n_in,
                              void* d_out, int out_size, void* d_ws, size_t ws_size,
                              hipStream_t stream)
{
    const int*   ei  = (const int*)d_in[0];
    const float* ew  = (const float*)d_in[1];
    const float* emb = (const float*)d_in[2];
    const float* Wx  = (const float*)d_in[3];
    const float* bx  = (const float*)d_in[4];
    const float* Wh  = (const float*)d_in[5];
    const float* bh  = (const float*)d_in[6];
    float* out = (float*)d_out;

    const int* src = ei;
    const int* dst = ei + EE;

    char* ws = (char*)d_ws;
    size_t off = 0;
    auto alloc = [&](size_t nbytes) -> char* {
        char* p = ws + off;
        off = (off + nbytes + 255) & ~(size_t)255;
        return p;
    };
    float*  deg     = (float*)alloc((size_t)NN * 4);
    float*  dinv    = (float*)alloc((size_t)NN * 4);
    int*    hist    = (int*)alloc((size_t)(NN + 1) * 4);
    int*    row_ptr = (int*)alloc((size_t)(NN + 1) * 4);
    int*    fill    = (int*)alloc((size_t)(NN + 1) * 4);
    int*    src_srt = (int*)alloc((size_t)EE * 4);
    float*  w_srt   = (float*)alloc((size_t)EE * 4);
    float*  tvec    = (float*)alloc((size_t)4 * NN * 4);
    float*  scol    = (float*)alloc((size_t)LL * 2 * KK * DD * 4);
    float*  X       = (float*)alloc((size_t)3 * NN * DD * 4);   // Xz,Xr,Xh fp32
    float*  Tf      = (float*)alloc((size_t)4 * NN * DD * 4);   // T1..T4 fp32
    ushort* WxT     = (ushort*)alloc((size_t)LL * 3 * KK * DD * DD * 2 * 2); // hi+lo
    ushort* WhT2    = (ushort*)alloc((size_t)LL * KK * DD * DD * 2 * 2);     // hi+lo
    (void)ws_size; (void)in_sizes; (void)n_in; (void)out_size;

    float* Xz = X;
    float* Xr = X + (size_t)NN * DD;
    float* Xh = X + (size_t)2 * NN * DD;
    float* T1 = Tf;
    float* T2 = Tf + (size_t)NN * DD;
    float* T3 = Tf + (size_t)2 * NN * DD;
    float* T4 = Tf + (size_t)3 * NN * DD;

    const int EG = (EE + 255) / 256;
    const int NG = (NN + 255) / 256;
    const int PG = (NN + 7) / 8;
    const int ELG = (NN * DD + 255) / 256;
    const int MMG = (NN + 127) / 128;
    const int GATE_STRIDE = KK * DD * DD * 2;  // ushorts per gate (hi+lo per k, K tiles)

    hipMemsetAsync(deg, 0, (size_t)NN * 4, stream);
    hipMemsetAsync(hist, 0, (size_t)(NN + 1) * 4, stream);

    edge_pass1<<<EG, 256, 0, stream>>>(src, dst, ew, deg, hist);
    dinv_kernel<<<NG, 256, 0, stream>>>(deg, dinv);
    scan_kernel<<<1, 1024, 0, stream>>>(hist, row_ptr);
    copy_fill<<<NG, 256, 0, stream>>>(row_ptr, fill);
    edge_scatter<<<EG, 256, 0, stream>>>(src, dst, ew, dinv, fill, src_srt, w_srt);

    // scalar Chebyshev vectors t1..t4 (t0 = ones, implicit)
    float* t1 = tvec;
    float* t2 = tvec + NN;
    float* t3 = tvec + 2 * NN;
    float* t4 = tvec + 3 * NN;
    propv_kernel<<<NG, 256, 0, stream>>>(row_ptr, src_srt, w_srt, nullptr, nullptr, t1, 1.f,  0.f, 1, 0);
    propv_kernel<<<NG, 256, 0, stream>>>(row_ptr, src_srt, w_srt, t1, nullptr,      t2, 2.f, -1.f, 0, 1);
    propv_kernel<<<NG, 256, 0, stream>>>(row_ptr, src_srt, w_srt, t2, t1,           t3, 2.f, -1.f, 0, 0);
    propv_kernel<<<NG, 256, 0, stream>>>(row_ptr, src_srt, w_srt, t3, t2,           t4, 2.f, -1.f, 0, 0);

    colsum_kernel<<<LL * 2 * KK, 128, 0, stream>>>(Wh, scol);

    // weights -> hi/lo bf16, transposed + pre-swizzled
    wconv_split<<<LL * 3 * KK, 256, 0, stream>>>(Wx, WxT, 0);
    wconv_split<<<LL * KK, 256, 0, stream>>>(Wh, WhT2, 1);

    const float* x_in = emb;
    for (int l = 0; l < LL; ++l) {
        // Chebyshev basis of x (fp32)
        prop_mat<<<PG, 256, 0, stream>>>(row_ptr, src_srt, w_srt, x_in, nullptr, T1, 1.f,  0.f);
        prop_mat<<<PG, 256, 0, stream>>>(row_ptr, src_srt, w_srt, T1,   x_in,    T2, 2.f, -1.f);
        prop_mat<<<PG, 256, 0, stream>>>(row_ptr, src_srt, w_srt, T2,   T1,      T3, 2.f, -1.f);
        prop_mat<<<PG, 256, 0, stream>>>(row_ptr, src_srt, w_srt, T3,   T2,      T4, 2.f, -1.f);

        // Xg = sum_k T_k @ Wx[l,g,k], g=0..2 (3-pass split MFMA, XCD co-located)
        cheb_mm_mfma<<<MMG * 3, 256, 0, stream>>>(x_in, T1, T2, T3, T4,
                                             WxT + (size_t)l * 3 * GATE_STRIDE, GATE_STRIDE,
                                             Xz, (size_t)NN * DD, 0, 3);

        // Z, R (rank-K ones-side cheb + biases), in place
        gate_zr_kernel<<<ELG, 256, 0, stream>>>(Xz, Xr, tvec, scol, bx, bh, l);

        // Chebyshev basis of R (H*R == R since H == ones)
        prop_mat<<<PG, 256, 0, stream>>>(row_ptr, src_srt, w_srt, Xr, nullptr, T1, 1.f,  0.f);
        prop_mat<<<PG, 256, 0, stream>>>(row_ptr, src_srt, w_srt, T1, Xr,      T2, 2.f, -1.f);
        prop_mat<<<PG, 256, 0, stream>>>(row_ptr, src_srt, w_srt, T2, T1,      T3, 2.f, -1.f);
        prop_mat<<<PG, 256, 0, stream>>>(row_ptr, src_srt, w_srt, T3, T2,      T4, 2.f, -1.f);

        // Xh += sum_k TR_k @ Wh[l,2,k]
        cheb_mm_mfma<<<MMG, 256, 0, stream>>>(Xr, T1, T2, T3, T4,
                                             WhT2 + (size_t)l * GATE_STRIDE, 0,
                                             Xh, 0, 1, 1);

        // h = relu(Z + (1-Z)*tanh(Xh + biases)) -> out (x for next layer)
        gate_final_kernel<<<ELG, 256, 0, stream>>>(Xz, Xh, bx, bh, l, out);
        x_in = out;
    }
}

// Round 5
// 890.820 us; speedup vs baseline: 2.6648x; 1.3733x over previous
//
#include <hip/hip_runtime.h>
#include <math.h>

#define NN 50000
#define EE 500000
#define DD 128
#define KK 5
#define LL 2

typedef _Float16 f16x8 __attribute__((ext_vector_type(8)));
typedef float f32x4 __attribute__((ext_vector_type(4)));

__device__ __forceinline__ ushort f2h(float x) {
    union { _Float16 h; ushort u; } v; v.h = (_Float16)x; return v.u;
}

// ===================== graph preprocessing =====================

__global__ __launch_bounds__(256) void edge_pass1(
    const int* __restrict__ src, const int* __restrict__ dst,
    const float* __restrict__ ew,
    float* __restrict__ deg, int* __restrict__ hist)
{
    int e = blockIdx.x * blockDim.x + threadIdx.x;
    if (e >= EE) return;
    atomicAdd(&deg[src[e]], ew[e]);
    atomicAdd(&hist[dst[e]], 1);
}

__global__ __launch_bounds__(256) void dinv_kernel(
    const float* __restrict__ deg, float* __restrict__ dinv)
{
    int i = blockIdx.x * blockDim.x + threadIdx.x;
    if (i >= NN) return;
    float d = deg[i];
    dinv[i] = (d > 0.f) ? (1.f / sqrtf(d)) : 0.f;
}

__global__ __launch_bounds__(1024) void scan_kernel(
    const int* __restrict__ hist, int* __restrict__ row_ptr)
{
    __shared__ int buf[1024];
    __shared__ int carry;
    int tid = threadIdx.x;
    if (tid == 0) { carry = 0; row_ptr[0] = 0; }
    __syncthreads();
    for (int base = 0; base < NN; base += 1024) {
        int i = base + tid;
        int v = (i < NN) ? hist[i] : 0;
        buf[tid] = v;
        __syncthreads();
        for (int off = 1; off < 1024; off <<= 1) {
            int t = (tid >= off) ? buf[tid - off] : 0;
            __syncthreads();
            buf[tid] += t;
            __syncthreads();
        }
        int incl = buf[tid] + carry;
        if (i < NN) row_ptr[i + 1] = incl;
        __syncthreads();
        if (tid == 1023) carry = incl;
        __syncthreads();
    }
}

__global__ __launch_bounds__(256) void copy_fill(
    const int* __restrict__ row_ptr, int* __restrict__ fill)
{
    int i = blockIdx.x * blockDim.x + threadIdx.x;
    if (i < NN) fill[i] = row_ptr[i];
}

__global__ __launch_bounds__(256) void edge_scatter(
    const int* __restrict__ src, const int* __restrict__ dst,
    const float* __restrict__ ew, const float* __restrict__ dinv,
    int* __restrict__ fill,
    int* __restrict__ src_srt, float* __restrict__ w_srt)
{
    int e = blockIdx.x * blockDim.x + threadIdx.x;
    if (e >= EE) return;
    int s = src[e], t = dst[e];
    float w = -dinv[s] * ew[e] * dinv[t];
    int pos = atomicAdd(&fill[t], 1);
    src_srt[pos] = s;
    w_srt[pos] = w;
}

// ===================== scalar Chebyshev vectors (for H = ones) =====================
__global__ __launch_bounds__(256) void propv_kernel(
    const int* __restrict__ rp, const int* __restrict__ ss, const float* __restrict__ sw,
    const float* __restrict__ tin, const float* __restrict__ tprev, float* __restrict__ tout,
    float alpha, float beta, int ones_in, int ones_prev)
{
    int i = blockIdx.x * blockDim.x + threadIdx.x;
    if (i >= NN) return;
    float acc = 0.f;
    int e0 = rp[i], e1 = rp[i + 1];
    int e = e0;
    for (; e + 4 <= e1; e += 4) {
        float t0 = ones_in ? 1.f : tin[ss[e]];
        float t1v = ones_in ? 1.f : tin[ss[e + 1]];
        float t2v = ones_in ? 1.f : tin[ss[e + 2]];
        float t3v = ones_in ? 1.f : tin[ss[e + 3]];
        acc += sw[e] * t0 + sw[e + 1] * t1v + sw[e + 2] * t2v + sw[e + 3] * t3v;
    }
    for (; e < e1; ++e) {
        float tv = ones_in ? 1.f : tin[ss[e]];
        acc += sw[e] * tv;
    }
    float pv = ones_prev ? 1.f : (tprev ? tprev[i] : 0.f);
    tout[i] = alpha * acc + beta * pv;
}

// colsum of Wh[l, g(0..1), k] -> scol[(l*2+g)*K + k][d]
__global__ __launch_bounds__(128) void colsum_kernel(
    const float* __restrict__ Wh, float* __restrict__ scol)
{
    int b = blockIdx.x;
    int k = b % KK;
    int g = (b / KK) % 2;
    int l = b / (2 * KK);
    int d = threadIdx.x;
    const float* Wp = Wh + ((size_t)((l * 3 + g) * KK + k)) * DD * DD;
    float s = 0.f;
    for (int r = 0; r < DD; ++r) s += Wp[r * DD + d];
    scol[((size_t)((l * 2 + g) * KK + k)) * DD + d] = s;
}

// ===================== weight convert: fp32 -> fp16, transposed + pre-swizzled ==
// dst tile t: 128x128 f16 swizzled (32KB). element (dout=rb, din=c) at byte
// rb*256 + ((c*2) ^ ((rb&7)<<4)).
// mode 0: src tile = t (Wx); mode 1: src tile = ((t/K)*3+2)*K + t%K (Wh gate 2)
__global__ __launch_bounds__(256) void wconv_f16(
    const float* __restrict__ W, ushort* __restrict__ out, int mode)
{
    int t = blockIdx.x;
    int st = (mode == 0) ? t : ((t / KK) * 3 + 2) * KK + (t % KK);
    const float* Wp = W + (size_t)st * DD * DD;
    ushort* op = out + (size_t)t * DD * DD;
    for (int idx = threadIdx.x; idx < DD * DD; idx += 256) {
        int rb = idx >> 7, c = idx & 127;
        float w = Wp[c * DD + rb];          // transpose: [dout][din] from [din][dout]
        int byte = rb * 256 + (((c * 2) ^ ((rb & 7) << 4)));
        *(ushort*)((char*)op + byte) = f2h(w);
    }
}

// ===================== f32 -> f16 bulk convert =====================
__global__ __launch_bounds__(256) void f32_to_f16(
    const float* __restrict__ in, ushort* __restrict__ out, int n8)
{
    int i = blockIdx.x * blockDim.x + threadIdx.x;
    if (i >= n8) return;
    float4 a = ((const float4*)in)[i * 2];
    float4 b = ((const float4*)in)[i * 2 + 1];
    f16x8 o;
    o[0] = (_Float16)a.x; o[1] = (_Float16)a.y; o[2] = (_Float16)a.z; o[3] = (_Float16)a.w;
    o[4] = (_Float16)b.x; o[5] = (_Float16)b.y; o[6] = (_Float16)b.z; o[7] = (_Float16)b.w;
    ((f16x8*)out)[i] = o;
}

// ===================== dense (N,D) fp16 propagation: out = alpha*L_hat@x + beta*prev ===
// 16 lanes per node, lane owns 8 cols (f16x8 = 16B loads); 4-edge unroll for MLP
__global__ __launch_bounds__(256) void prop_mat(
    const int* __restrict__ rp, const int* __restrict__ ss, const float* __restrict__ sw,
    const ushort* __restrict__ x, const ushort* __restrict__ prev,
    ushort* __restrict__ out, float alpha, float beta)
{
    int node = blockIdx.x * 16 + (threadIdx.x >> 4);
    if (node >= NN) return;
    int lane = threadIdx.x & 15;
    int c = lane * 8;
    float acc[8];
#pragma unroll
    for (int j = 0; j < 8; ++j) acc[j] = 0.f;
    int e0 = rp[node], e1 = rp[node + 1];
    int e = e0;
    for (; e + 4 <= e1; e += 4) {
        int s0 = ss[e], s1 = ss[e + 1], s2 = ss[e + 2], s3 = ss[e + 3];
        float w0 = sw[e], w1 = sw[e + 1], w2 = sw[e + 2], w3 = sw[e + 3];
        f16x8 r0 = *(const f16x8*)(x + (size_t)s0 * DD + c);
        f16x8 r1 = *(const f16x8*)(x + (size_t)s1 * DD + c);
        f16x8 r2 = *(const f16x8*)(x + (size_t)s2 * DD + c);
        f16x8 r3 = *(const f16x8*)(x + (size_t)s3 * DD + c);
#pragma unroll
        for (int j = 0; j < 8; ++j)
            acc[j] += w0 * (float)r0[j] + w1 * (float)r1[j] + w2 * (float)r2[j] + w3 * (float)r3[j];
    }
    for (; e < e1; ++e) {
        int s = ss[e];
        float w = sw[e];
        f16x8 r = *(const f16x8*)(x + (size_t)s * DD + c);
#pragma unroll
        for (int j = 0; j < 8; ++j) acc[j] += w * (float)r[j];
    }
    f16x8 o;
    if (beta != 0.f && prev) {
        f16x8 pv = *(const f16x8*)(prev + (size_t)node * DD + c);
#pragma unroll
        for (int j = 0; j < 8; ++j) o[j] = (_Float16)(alpha * acc[j] + beta * (float)pv[j]);
    } else {
#pragma unroll
        for (int j = 0; j < 8; ++j) o[j] = (_Float16)(alpha * acc[j]);
    }
    *(f16x8*)(out + (size_t)node * DD + c) = o;
}

// ===================== fp16 MFMA Chebyshev matmul =====================
// out(g) = [accumulate? out(g):0] + sum_k T_k @ W(g,k)  (single-pass f16 MFMA)
// 1D grid = ntile*ngates with bijective XCD-chunked swizzle so the ngates
// gate-blocks of one row-tile co-locate on one XCD (share A in L2).
__global__ __launch_bounds__(256) void cheb_mm_mfma(
    const ushort* __restrict__ T0, const ushort* __restrict__ T1,
    const ushort* __restrict__ T2, const ushort* __restrict__ T3,
    const ushort* __restrict__ T4,
    const ushort* __restrict__ Wt, int gate_stride,   // ushorts between gates
    float* __restrict__ outbase, size_t out_stride, int accumulate, int ngates)
{
    __shared__ ushort Bs[DD * DD];  // 32KB, pre-swizzled f16 W tile

    // XCD-chunked bijective swizzle (m204)
    const int nwg = gridDim.x;
    const int b = blockIdx.x;
    const int xcd = b & 7, idx = b >> 3;
    const int q = nwg >> 3, rr = nwg & 7;
    const int start = (xcd < rr) ? xcd * (q + 1) : rr * (q + 1) + (xcd - rr) * q;
    const int lin = start + idx;
    const int tile = lin / ngates;
    const int g = lin - tile * ngates;

    const int tid = threadIdx.x;
    const int lane = tid & 63;
    const int wid = tid >> 6;
    const int lr = lane & 15;
    const int lk = lane >> 4;
    const int r0 = tile * 128;
    const ushort* Wg = Wt + (size_t)g * gate_stride;
    const ushort* Ts[5] = {T0, T1, T2, T3, T4};

    f32x4 acc[2][8];
#pragma unroll
    for (int fr = 0; fr < 2; ++fr)
#pragma unroll
        for (int fc = 0; fc < 8; ++fc)
            acc[fr][fc] = (f32x4){0.f, 0.f, 0.f, 0.f};

    int rowg0 = r0 + wid * 32 + lr;
    int rowg1 = rowg0 + 16;
    bool ok0 = rowg0 < NN;
    bool ok1 = rowg1 < NN;

#pragma unroll
    for (int k = 0; k < KK; ++k) {
        const ushort* Tk = Ts[k];
        const ushort* Bg = Wg + (size_t)k * (DD * DD);
        __syncthreads();
        // stage 32KB linear (global layout already swizzled)
#pragma unroll
        for (int i = 0; i < 8; ++i) {
            int off = i * 4096 + tid * 16;
            uint4 v = *(const uint4*)((const char*)Bg + off);
            *(uint4*)((char*)Bs + off) = v;
        }
        // A: f16 global loads (16B = full 8-elem k-chunk per lane)
        f16x8 a[2][4];
#pragma unroll
        for (int fr = 0; fr < 2; ++fr) {
            int rowg = fr ? rowg1 : rowg0;
            bool ok = fr ? ok1 : ok0;
            const ushort* rp2 = Tk + (size_t)rowg * DD + lk * 8;
#pragma unroll
            for (int ko = 0; ko < 4; ++ko) {
                if (ok) a[fr][ko] = *(const f16x8*)(rp2 + ko * 32);
                else a[fr][ko] = (f16x8){0, 0, 0, 0, 0, 0, 0, 0};
            }
        }
        __syncthreads();
#pragma unroll
        for (int ko = 0; ko < 4; ++ko) {
            const int cb = ko * 64 + lk * 16;
#pragma unroll
            for (int fc = 0; fc < 8; ++fc) {
                int rb = fc * 16 + lr;
                int byte = (rb * 256 + cb) ^ ((rb & 7) << 4);
                f16x8 bfrag = *(const f16x8*)((const char*)Bs + byte);
                acc[0][fc] = __builtin_amdgcn_mfma_f32_16x16x32_f16(a[0][ko], bfrag, acc[0][fc], 0, 0, 0);
                acc[1][fc] = __builtin_amdgcn_mfma_f32_16x16x32_f16(a[1][ko], bfrag, acc[1][fc], 0, 0, 0);
            }
        }
    }

    float* outp = outbase + (size_t)g * out_stride;
#pragma unroll
    for (int fr = 0; fr < 2; ++fr) {
#pragma unroll
        for (int j = 0; j < 4; ++j) {
            int grow = r0 + wid * 32 + fr * 16 + lk * 4 + j;
            if (grow < NN) {
#pragma unroll
                for (int fc = 0; fc < 8; ++fc) {
                    int col = fc * 16 + lr;
                    float* p = outp + (size_t)grow * DD + col;
                    float v = acc[fr][fc][j];
                    if (accumulate) *p += v; else *p = v;
                }
            }
        }
    }
}

// ===================== gate kernels =====================
__global__ __launch_bounds__(256) void gate_zr_kernel(
    float* __restrict__ Xz, float* __restrict__ Xr, ushort* __restrict__ Xr_f16,
    const float* __restrict__ tvec, const float* __restrict__ scol,
    const float* __restrict__ bx, const float* __restrict__ bh, int l)
{
    int idx = blockIdx.x * blockDim.x + threadIdx.x;
    if (idx >= NN * DD) return;
    int i = idx >> 7;
    int d = idx & 127;
    float t1 = tvec[i], t2 = tvec[NN + i], t3 = tvec[2 * NN + i], t4 = tvec[3 * NN + i];

    const float* s0 = scol + (size_t)((l * 2 + 0) * KK) * DD;
    float hz = s0[d] + t1 * s0[DD + d] + t2 * s0[2 * DD + d] + t3 * s0[3 * DD + d] + t4 * s0[4 * DD + d];
    float z = Xz[idx] + bx[(l * 3 + 0) * DD + d] + bh[(l * 3 + 0) * DD + d] + hz;
    Xz[idx] = 1.f / (1.f + expf(-z));

    const float* s1 = scol + (size_t)((l * 2 + 1) * KK) * DD;
    float hr = s1[d] + t1 * s1[DD + d] + t2 * s1[2 * DD + d] + t3 * s1[3 * DD + d] + t4 * s1[4 * DD + d];
    float r = Xr[idx] + bx[(l * 3 + 1) * DD + d] + bh[(l * 3 + 1) * DD + d] + hr;
    float rv = 1.f / (1.f + expf(-r));
    Xr[idx] = rv;
    Xr_f16[idx] = f2h(rv);
}

__global__ __launch_bounds__(256) void gate_final_kernel(
    const float* __restrict__ Xz, const float* __restrict__ Xh,
    const float* __restrict__ bx, const float* __restrict__ bh, int l,
    float* __restrict__ out, ushort* __restrict__ h_f16)
{
    int idx = blockIdx.x * blockDim.x + threadIdx.x;
    if (idx >= NN * DD) return;
    int d = idx & 127;
    float ht = tanhf(Xh[idx] + bx[(l * 3 + 2) * DD + d] + bh[(l * 3 + 2) * DD + d]);
    float z = Xz[idx];
    float hn = z + (1.f - z) * ht;
    float h = hn > 0.f ? hn : 0.f;
    out[idx] = h;
    h_f16[idx] = f2h(h);
}

// ===================== host orchestration =====================

extern "C" void kernel_launch(void* const* d_in, const int* in_sizes, int n_in,
                              void* d_out, int out_size, void* d_ws, size_t ws_size,
                              hipStream_t stream)
{
    const int*   ei  = (const int*)d_in[0];
    const float* ew  = (const float*)d_in[1];
    const float* emb = (const float*)d_in[2];
    const float* Wx  = (const float*)d_in[3];
    const float* bx  = (const float*)d_in[4];
    const float* Wh  = (const float*)d_in[5];
    const float* bh  = (const float*)d_in[6];
    float* out = (float*)d_out;

    const int* src = ei;
    const int* dst = ei + EE;

    char* ws = (char*)d_ws;
    size_t off = 0;
    auto alloc = [&](size_t nbytes) -> char* {
        char* p = ws + off;
        off = (off + nbytes + 255) & ~(size_t)255;
        return p;
    };
    float*  deg     = (float*)alloc((size_t)NN * 4);
    float*  dinv    = (float*)alloc((size_t)NN * 4);
    int*    hist    = (int*)alloc((size_t)(NN + 1) * 4);
    int*    row_ptr = (int*)alloc((size_t)(NN + 1) * 4);
    int*    fill    = (int*)alloc((size_t)(NN + 1) * 4);
    int*    src_srt = (int*)alloc((size_t)EE * 4);
    float*  w_srt   = (float*)alloc((size_t)EE * 4);
    float*  tvec    = (float*)alloc((size_t)4 * NN * 4);
    float*  scol    = (float*)alloc((size_t)LL * 2 * KK * DD * 4);
    float*  X       = (float*)alloc((size_t)3 * NN * DD * 4);    // Xz,Xr,Xh fp32
    ushort* Th      = (ushort*)alloc((size_t)4 * NN * DD * 2);   // T1..T4 f16
    ushort* x_f16   = (ushort*)alloc((size_t)NN * DD * 2);
    ushort* Xr_f16  = (ushort*)alloc((size_t)NN * DD * 2);
    ushort* WxT     = (ushort*)alloc((size_t)LL * 3 * KK * DD * DD * 2);
    ushort* WhT2    = (ushort*)alloc((size_t)LL * KK * DD * DD * 2);
    (void)ws_size; (void)in_sizes; (void)n_in; (void)out_size;

    float* Xz = X;
    float* Xr = X + (size_t)NN * DD;
    float* Xh = X + (size_t)2 * NN * DD;
    ushort* T1 = Th;
    ushort* T2 = Th + (size_t)NN * DD;
    ushort* T3 = Th + (size_t)2 * NN * DD;
    ushort* T4 = Th + (size_t)3 * NN * DD;

    const int EG = (EE + 255) / 256;
    const int NG = (NN + 255) / 256;
    const int PG = (NN + 15) / 16;
    const int ELG = (NN * DD + 255) / 256;
    const int MMG = (NN + 127) / 128;
    const int CVG = (NN * DD / 8 + 255) / 256;
    const int GATE_STRIDE = KK * DD * DD;  // ushorts per gate

    hipMemsetAsync(deg, 0, (size_t)NN * 4, stream);
    hipMemsetAsync(hist, 0, (size_t)(NN + 1) * 4, stream);

    edge_pass1<<<EG, 256, 0, stream>>>(src, dst, ew, deg, hist);
    dinv_kernel<<<NG, 256, 0, stream>>>(deg, dinv);
    scan_kernel<<<1, 1024, 0, stream>>>(hist, row_ptr);
    copy_fill<<<NG, 256, 0, stream>>>(row_ptr, fill);
    edge_scatter<<<EG, 256, 0, stream>>>(src, dst, ew, dinv, fill, src_srt, w_srt);

    // scalar Chebyshev vectors t1..t4 (t0 = ones, implicit)
    float* t1 = tvec;
    float* t2 = tvec + NN;
    float* t3 = tvec + 2 * NN;
    float* t4 = tvec + 3 * NN;
    propv_kernel<<<NG, 256, 0, stream>>>(row_ptr, src_srt, w_srt, nullptr, nullptr, t1, 1.f,  0.f, 1, 0);
    propv_kernel<<<NG, 256, 0, stream>>>(row_ptr, src_srt, w_srt, t1, nullptr,      t2, 2.f, -1.f, 0, 1);
    propv_kernel<<<NG, 256, 0, stream>>>(row_ptr, src_srt, w_srt, t2, t1,           t3, 2.f, -1.f, 0, 0);
    propv_kernel<<<NG, 256, 0, stream>>>(row_ptr, src_srt, w_srt, t3, t2,           t4, 2.f, -1.f, 0, 0);

    colsum_kernel<<<LL * 2 * KK, 128, 0, stream>>>(Wh, scol);

    // weights -> f16, transposed + pre-swizzled
    wconv_f16<<<LL * 3 * KK, 256, 0, stream>>>(Wx, WxT, 0);
    wconv_f16<<<LL * KK, 256, 0, stream>>>(Wh, WhT2, 1);

    // emb -> f16
    f32_to_f16<<<CVG, 256, 0, stream>>>(emb, x_f16, NN * DD / 8);

    for (int l = 0; l < LL; ++l) {
        // Chebyshev basis of x (f16 storage, fp32 accumulate)
        prop_mat<<<PG, 256, 0, stream>>>(row_ptr, src_srt, w_srt, x_f16, nullptr, T1, 1.f,  0.f);
        prop_mat<<<PG, 256, 0, stream>>>(row_ptr, src_srt, w_srt, T1,    x_f16,   T2, 2.f, -1.f);
        prop_mat<<<PG, 256, 0, stream>>>(row_ptr, src_srt, w_srt, T2,    T1,      T3, 2.f, -1.f);
        prop_mat<<<PG, 256, 0, stream>>>(row_ptr, src_srt, w_srt, T3,    T2,      T4, 2.f, -1.f);

        // Xg = sum_k T_k @ Wx[l,g,k], g=0..2 (f16 MFMA, XCD co-located)
        cheb_mm_mfma<<<MMG * 3, 256, 0, stream>>>(x_f16, T1, T2, T3, T4,
                                             WxT + (size_t)l * 3 * GATE_STRIDE, GATE_STRIDE,
                                             Xz, (size_t)NN * DD, 0, 3);

        // Z, R (rank-K ones-side cheb + biases); writes R f16 mirror
        gate_zr_kernel<<<ELG, 256, 0, stream>>>(Xz, Xr, Xr_f16, tvec, scol, bx, bh, l);

        // Chebyshev basis of R (H*R == R since H == ones)
        prop_mat<<<PG, 256, 0, stream>>>(row_ptr, src_srt, w_srt, Xr_f16, nullptr, T1, 1.f,  0.f);
        prop_mat<<<PG, 256, 0, stream>>>(row_ptr, src_srt, w_srt, T1,     Xr_f16,  T2, 2.f, -1.f);
        prop_mat<<<PG, 256, 0, stream>>>(row_ptr, src_srt, w_srt, T2,     T1,      T3, 2.f, -1.f);
        prop_mat<<<PG, 256, 0, stream>>>(row_ptr, src_srt, w_srt, T3,     T2,      T4, 2.f, -1.f);

        // Xh += sum_k TR_k @ Wh[l,2,k]
        cheb_mm_mfma<<<MMG, 256, 0, stream>>>(Xr_f16, T1, T2, T3, T4,
                                             WhT2 + (size_t)l * GATE_STRIDE, 0,
                                             Xh, 0, 1, 1);

        // h = relu(Z + (1-Z)*tanh(Xh + biases)) -> out (+ f16 mirror = next layer x)
        gate_final_kernel<<<ELG, 256, 0, stream>>>(Xz, Xh, bx, bh, l, out, x_f16);
    }
}